// Round 1
// baseline (547.730 us; speedup 1.0000x reference)
//
#include <hip/hip_runtime.h>
#include <hip/hip_cooperative_groups.h>
#include <stdint.h>

namespace cg = cooperative_groups;

#define SPARSE_D 41
#define SPARSE_H 1600
#define SPARSE_W 1408
#define BN_EPS 0.001f

static constexpr int NYB = SPARSE_H / 2;          // 800
static constexpr int NBUCKET = SPARSE_D * NYB;    // 32,800
static constexpr int PCAP = 12;                   // max non-self pairs per voxel (lambda~0.056)

// bucket = z*NYB + (y>>1): 32 uint32 words (128B). word0 = count, words 1..31 = entries.
// entry: [29]=y&1, [28:18]=x (11b), [17:0]=idx ; pair: [22:18]=k, [17:0]=idx

// ============================================================================
// ======================  FUSED COOPERATIVE PATH  ============================
// ============================================================================

// accumulate per-voxel stats into block-shared [4][33] rows (wave-shuffle reduce)
__device__ __forceinline__ void acc_stats(const float acc[16], float (*smem)[33]) {
    int lid = threadIdx.x & 63;
    int wid = threadIdx.x >> 6;
    #pragma unroll
    for (int d = 0; d < 16; ++d) {
        float v = acc[d];
        float v2 = v * v;
        #pragma unroll
        for (int off = 32; off; off >>= 1) {
            v  += __shfl_xor(v, off);
            v2 += __shfl_xor(v2, off);
        }
        if (lid == 0) { smem[wid][d] += v; smem[wid][16 + d] += v2; }
    }
}

// every block redundantly reduces partials[gridDim][32] -> sc/sh in LDS (L2-hot, ~2us aggregate)
__device__ __forceinline__ void block_finalize(const float* __restrict__ partials, int nbk,
                                               const float* __restrict__ gamma,
                                               const float* __restrict__ beta,
                                               float invN, float (*smem)[33],
                                               float* __restrict__ sc, float* __restrict__ sh) {
    int ch = threadIdx.x & 31, rg = threadIdx.x >> 5;   // 8 row-groups x 32 channels
    float s0 = 0.f, s1 = 0.f, s2 = 0.f, s3 = 0.f;
    int j = rg;
    for (; j + 24 < nbk; j += 32) {
        s0 += partials[(size_t)(j     ) * 32 + ch];
        s1 += partials[(size_t)(j +  8) * 32 + ch];
        s2 += partials[(size_t)(j + 16) * 32 + ch];
        s3 += partials[(size_t)(j + 24) * 32 + ch];
    }
    for (; j < nbk; j += 8) s0 += partials[(size_t)j * 32 + ch];
    __syncthreads();
    smem[rg][ch] = (s0 + s1) + (s2 + s3);
    __syncthreads();
    if (threadIdx.x < 32) {
        float t = 0.f;
        #pragma unroll
        for (int r = 0; r < 8; ++r) t += smem[r][threadIdx.x];
        smem[0][threadIdx.x] = t;   // column-exclusive: thread i only touches col i
    }
    __syncthreads();
    if (threadIdx.x < 16) {
        int d = threadIdx.x;
        float mean = smem[0][d] * invN;
        float var  = smem[0][16 + d] * invN - mean * mean;
        float s2c  = gamma[d] * rsqrtf(var + BN_EPS);
        sc[d] = s2c;
        sh[d] = beta[d] - mean * s2c;
    }
    __syncthreads();
}

__global__ void __launch_bounds__(256, 2)
k_fused(const float* __restrict__ feat, const int* __restrict__ coords,
        const float* __restrict__ w1, const float* __restrict__ gamma1,
        const float* __restrict__ beta1, const float* __restrict__ w2,
        const float* __restrict__ gamma2, const float* __restrict__ beta2,
        float* __restrict__ out, uint32_t* __restrict__ bent, int* __restrict__ pcnt,
        uint32_t* __restrict__ pairs, float* __restrict__ h1,
        float* __restrict__ p1, float* __restrict__ p2, int N, float invN) {
    cg::grid_group grid = cg::this_grid();
    __shared__ float smem[8][33];
    __shared__ float sc[16], sh[16];
    const int G   = (int)gridDim.x * 256;
    const int tid = (int)blockIdx.x * 256 + (int)threadIdx.x;

    // ---------------- phase 0: zero bucket array (coalesced uint4) ----------------
    for (int i = tid; i < NBUCKET * 8; i += G)
        ((uint4*)bent)[i] = make_uint4(0u, 0u, 0u, 0u);
    __threadfence();
    grid.sync();

    // ---------------- phase 1: scatter voxels into buckets ----------------
    for (int n = tid; n < N; n += G) {
        int4 c4 = ((const int4*)coords)[n];
        int z = c4.y, y = c4.z, x = c4.w;
        int b = z * NYB + (y >> 1);
        uint32_t e = ((uint32_t)(y & 1) << 29) | ((uint32_t)x << 18) | (uint32_t)n;
        int slot = atomicAdd((int*)&bent[(size_t)b * 32], 1) + 1;
        if (slot <= 31) bent[(size_t)b * 32 + slot] = e;
    }
    __threadfence();
    grid.sync();

    // ---------------- phase 2: build pairs + conv1 (3->16) + BN1 stats ----------------
    for (int i = threadIdx.x; i < 8 * 33; i += 256) ((float*)smem)[i] = 0.f;
    __syncthreads();
    const int nit = (N + G - 1) / G;   // uniform trip count: shuffles never diverge
    for (int it = 0; it < nit; ++it) {
        int n = tid + it * G;
        float acc[16];
        #pragma unroll
        for (int d = 0; d < 16; ++d) acc[d] = 0.f;
        if (n < N) {
            int4 c4 = ((const int4*)coords)[n];
            int z = c4.y, y = c4.z, x = c4.w;

            // self term first (uniform weight pointer -> scalar loads)
            float f0 = feat[n * 3 + 0], f1 = feat[n * 3 + 1], f2 = feat[n * 3 + 2];
            const float* wd = w1 + 13 * 48;
            #pragma unroll
            for (int d = 0; d < 16; ++d)
                acc[d] = fmaf(f0, wd[d], fmaf(f1, wd[16 + d], f2 * wd[32 + d]));

            // preload all 6 bucket line0s unconditionally (masked -> bucket 0) for MLP
            int yb0 = (y - 1) >> 1;
            uint4 q0[6];
            int bix[6], mm[6];
            #pragma unroll
            for (int p = 0; p < 6; ++p) {
                int zz = z + p / 2 - 1;
                int yb = yb0 + (p & 1);
                bool v = ((unsigned)zz < SPARSE_D) & ((unsigned)yb < NYB);
                int b = v ? (zz * NYB + yb) : 0;
                bix[p] = b;
                q0[p] = *(const uint4*)&bent[(size_t)b * 32];
                mm[p] = v ? 1 : 0;
            }

            uint32_t lpairs[PCAP];
            int cnt = 0;
            #pragma unroll
            for (int p = 0; p < 6; ++p) {
                int m = mm[p] ? min((int)q0[p].x, 31) : 0;
                int yb = yb0 + (p & 1);
                int dzk = (p / 2) * 9;
                auto scan_entry = [&](uint32_t e, int slot) {
                    if (slot > m) return;
                    int ey = (yb << 1) + (int)(e >> 29);
                    int ex = (int)((e >> 18) & 0x7FFu);
                    int dy = ey - y, dx = ex - x;
                    if ((unsigned)(dy + 1) > 2u || (unsigned)(dx + 1) > 2u) return;
                    uint32_t idx = e & 0x3FFFFu;
                    if (idx == (uint32_t)n) return;
                    int k = dzk + (dy + 1) * 3 + (dx + 1);
                    if (cnt < PCAP) lpairs[cnt] = ((uint32_t)k << 18) | idx;
                    ++cnt;
                };
                scan_entry(q0[p].y, 1);
                scan_entry(q0[p].z, 2);
                scan_entry(q0[p].w, 3);
                for (int w = 4; w <= m; w += 4) {
                    uint4 q = *(const uint4*)&bent[(size_t)bix[p] * 32 + w];
                    scan_entry(q.x, w);
                    scan_entry(q.y, w + 1);
                    scan_entry(q.z, w + 2);
                    scan_entry(q.w, w + 3);
                }
            }
            cnt = min(cnt, PCAP);
            pcnt[n] = cnt;
            for (int c = 0; c < cnt; ++c) {
                uint32_t pr = lpairs[c];
                pairs[(size_t)c * N + n] = pr;
                int k = (int)(pr >> 18), idx = (int)(pr & 0x3FFFFu);
                float g0 = feat[idx * 3 + 0], g1 = feat[idx * 3 + 1], g2 = feat[idx * 3 + 2];
                const float* wk = w1 + k * 48;
                #pragma unroll
                for (int d = 0; d < 16; ++d)
                    acc[d] = fmaf(g0, wk[d], fmaf(g1, wk[16 + d], fmaf(g2, wk[32 + d], acc[d])));
            }
            float4* o = (float4*)&h1[(size_t)n * 16];
            o[0] = make_float4(acc[0], acc[1], acc[2], acc[3]);
            o[1] = make_float4(acc[4], acc[5], acc[6], acc[7]);
            o[2] = make_float4(acc[8], acc[9], acc[10], acc[11]);
            o[3] = make_float4(acc[12], acc[13], acc[14], acc[15]);
        }
        acc_stats(acc, smem);
    }
    __syncthreads();
    if (threadIdx.x < 32)
        p1[(size_t)blockIdx.x * 32 + threadIdx.x] =
            smem[0][threadIdx.x] + smem[1][threadIdx.x] +
            smem[2][threadIdx.x] + smem[3][threadIdx.x];
    __threadfence();
    grid.sync();

    // ---------------- phase 3a: every block computes BN1 scale/shift ----------------
    block_finalize(p1, (int)gridDim.x, gamma1, beta1, invN, smem, sc, sh);
    __syncthreads();
    for (int i = threadIdx.x; i < 8 * 33; i += 256) ((float*)smem)[i] = 0.f;
    __syncthreads();

    // ---------------- phase 3b: conv2 (16->16, BN1+ReLU fused on load) + BN2 stats ----
    for (int it = 0; it < nit; ++it) {
        int n = tid + it * G;
        float acc[16];
        #pragma unroll
        for (int d = 0; d < 16; ++d) acc[d] = 0.f;
        if (n < N) {
            float g[16];
            #pragma unroll
            for (int c = 0; c < 16; c += 4) {
                float4 t = *(const float4*)&h1[(size_t)n * 16 + c];
                g[c]     = fmaxf(fmaf(t.x, sc[c],     sh[c]),     0.f);
                g[c + 1] = fmaxf(fmaf(t.y, sc[c + 1], sh[c + 1]), 0.f);
                g[c + 2] = fmaxf(fmaf(t.z, sc[c + 2], sh[c + 2]), 0.f);
                g[c + 3] = fmaxf(fmaf(t.w, sc[c + 3], sh[c + 3]), 0.f);
            }
            {
                const float* w = w2 + 13 * 256;    // uniform -> scalar-cache loads
                #pragma unroll
                for (int c = 0; c < 16; ++c)
                    #pragma unroll
                    for (int d = 0; d < 16; ++d)
                        acc[d] = fmaf(g[c], w[c * 16 + d], acc[d]);
            }
            int m = min(pcnt[n], PCAP);
            for (int cc = 0; cc < m; ++cc) {
                uint32_t pr = pairs[(size_t)cc * N + n];
                int k = (int)(pr >> 18), idx = (int)(pr & 0x3FFFFu);
                #pragma unroll
                for (int c = 0; c < 16; c += 4) {
                    float4 t = *(const float4*)&h1[(size_t)idx * 16 + c];
                    g[c]     = fmaxf(fmaf(t.x, sc[c],     sh[c]),     0.f);
                    g[c + 1] = fmaxf(fmaf(t.y, sc[c + 1], sh[c + 1]), 0.f);
                    g[c + 2] = fmaxf(fmaf(t.z, sc[c + 2], sh[c + 2]), 0.f);
                    g[c + 3] = fmaxf(fmaf(t.w, sc[c + 3], sh[c + 3]), 0.f);
                }
                const float* wk = w2 + k * 256;
                #pragma unroll
                for (int c = 0; c < 16; ++c)
                    #pragma unroll
                    for (int d = 0; d < 16; ++d)
                        acc[d] = fmaf(g[c], wk[c * 16 + d], acc[d]);
            }
            float4* o = (float4*)&out[(size_t)n * 16];
            o[0] = make_float4(acc[0], acc[1], acc[2], acc[3]);
            o[1] = make_float4(acc[4], acc[5], acc[6], acc[7]);
            o[2] = make_float4(acc[8], acc[9], acc[10], acc[11]);
            o[3] = make_float4(acc[12], acc[13], acc[14], acc[15]);
        }
        acc_stats(acc, smem);
    }
    __syncthreads();
    if (threadIdx.x < 32)
        p2[(size_t)blockIdx.x * 32 + threadIdx.x] =
            smem[0][threadIdx.x] + smem[1][threadIdx.x] +
            smem[2][threadIdx.x] + smem[3][threadIdx.x];
    __threadfence();
    grid.sync();

    // ---------------- phase 4: BN2 scale/shift + in-place BN+ReLU on out ----------------
    block_finalize(p2, (int)gridDim.x, gamma2, beta2, invN, smem, sc, sh);
    for (int i = tid; i < N * 4; i += G) {
        float4 v = ((float4*)out)[i];
        int c0 = (i & 3) * 4;
        v.x = fmaxf(fmaf(v.x, sc[c0 + 0], sh[c0 + 0]), 0.f);
        v.y = fmaxf(fmaf(v.y, sc[c0 + 1], sh[c0 + 1]), 0.f);
        v.z = fmaxf(fmaf(v.z, sc[c0 + 2], sh[c0 + 2]), 0.f);
        v.w = fmaxf(fmaf(v.w, sc[c0 + 3], sh[c0 + 3]), 0.f);
        ((float4*)out)[i] = v;
    }
}

// ============================================================================
// ======================  FALLBACK MULTI-KERNEL PATH  ========================
// ============================================================================

__global__ void k_insert(const int* __restrict__ coords, uint32_t* __restrict__ bent, int N) {
    int n = blockIdx.x * blockDim.x + threadIdx.x;
    if (n >= N) return;
    int4 c4 = ((const int4*)coords)[n];
    int z = c4.y, y = c4.z, x = c4.w;
    int b = z * NYB + (y >> 1);
    uint32_t e = ((uint32_t)(y & 1) << 29) | ((uint32_t)x << 18) | (uint32_t)n;
    int slot = atomicAdd((int*)&bent[(size_t)b * 32], 1) + 1;
    if (slot <= 31) bent[(size_t)b * 32 + slot] = e;
}

__device__ __forceinline__ void stats_epilogue(const float acc[16],
                                               float* __restrict__ partials,
                                               float (*sred)[32]) {
    int lid = threadIdx.x & 63;
    int wid = threadIdx.x >> 6;
    #pragma unroll
    for (int d = 0; d < 16; ++d) {
        float v = acc[d];
        float v2 = v * v;
        #pragma unroll
        for (int off = 32; off; off >>= 1) {
            v += __shfl_xor(v, off);
            v2 += __shfl_xor(v2, off);
        }
        if (lid == 0) { sred[wid][d] = v; sred[wid][16 + d] = v2; }
    }
    __syncthreads();
    if (threadIdx.x < 32)
        partials[(size_t)blockIdx.x * 32 + threadIdx.x] =
            sred[0][threadIdx.x] + sred[1][threadIdx.x] +
            sred[2][threadIdx.x] + sred[3][threadIdx.x];
}

__global__ void k_build_conv1(const int* __restrict__ coords, const uint32_t* __restrict__ bent,
                              const float* __restrict__ feat, const float* __restrict__ w1,
                              int* __restrict__ pcnt, uint32_t* __restrict__ pairs,
                              float* __restrict__ h1, float* __restrict__ partials, int N) {
    __shared__ float sred[4][32];
    int n = blockIdx.x * blockDim.x + threadIdx.x;
    float acc[16];
    #pragma unroll
    for (int d = 0; d < 16; ++d) acc[d] = 0.f;
    if (n < N) {
        int4 c4 = ((const int4*)coords)[n];
        int z = c4.y, y = c4.z, x = c4.w;
        float f0 = feat[n * 3 + 0], f1 = feat[n * 3 + 1], f2 = feat[n * 3 + 2];
        const float* wd = w1 + 13 * 48;
        #pragma unroll
        for (int d = 0; d < 16; ++d)
            acc[d] = fmaf(f0, wd[d], fmaf(f1, wd[16 + d], f2 * wd[32 + d]));
        int yb0 = (y - 1) >> 1;
        uint4 q0[6];
        int bix[6], mm[6];
        #pragma unroll
        for (int p = 0; p < 6; ++p) {
            int zz = z + p / 2 - 1;
            int yb = yb0 + (p & 1);
            bool v = ((unsigned)zz < SPARSE_D) & ((unsigned)yb < NYB);
            int b = v ? (zz * NYB + yb) : 0;
            bix[p] = b;
            q0[p] = *(const uint4*)&bent[(size_t)b * 32];
            mm[p] = v ? 1 : 0;
        }
        uint32_t lpairs[PCAP];
        int cnt = 0;
        #pragma unroll
        for (int p = 0; p < 6; ++p) {
            int m = mm[p] ? min((int)q0[p].x, 31) : 0;
            int yb = yb0 + (p & 1);
            int dzk = (p / 2) * 9;
            auto scan_entry = [&](uint32_t e, int slot) {
                if (slot > m) return;
                int ey = (yb << 1) + (int)(e >> 29);
                int ex = (int)((e >> 18) & 0x7FFu);
                int dy = ey - y, dx = ex - x;
                if ((unsigned)(dy + 1) > 2u || (unsigned)(dx + 1) > 2u) return;
                uint32_t idx = e & 0x3FFFFu;
                if (idx == (uint32_t)n) return;
                int k = dzk + (dy + 1) * 3 + (dx + 1);
                if (cnt < PCAP) lpairs[cnt] = ((uint32_t)k << 18) | idx;
                ++cnt;
            };
            scan_entry(q0[p].y, 1);
            scan_entry(q0[p].z, 2);
            scan_entry(q0[p].w, 3);
            for (int w = 4; w <= m; w += 4) {
                uint4 q = *(const uint4*)&bent[(size_t)bix[p] * 32 + w];
                scan_entry(q.x, w);
                scan_entry(q.y, w + 1);
                scan_entry(q.z, w + 2);
                scan_entry(q.w, w + 3);
            }
        }
        cnt = min(cnt, PCAP);
        pcnt[n] = cnt;
        for (int c = 0; c < cnt; ++c) {
            uint32_t pr = lpairs[c];
            pairs[(size_t)c * N + n] = pr;
            int k = (int)(pr >> 18), idx = (int)(pr & 0x3FFFFu);
            float g0 = feat[idx * 3 + 0], g1 = feat[idx * 3 + 1], g2 = feat[idx * 3 + 2];
            const float* wk = w1 + k * 48;
            #pragma unroll
            for (int d = 0; d < 16; ++d)
                acc[d] = fmaf(g0, wk[d], fmaf(g1, wk[16 + d], fmaf(g2, wk[32 + d], acc[d])));
        }
        float4* o = (float4*)&h1[(size_t)n * 16];
        o[0] = make_float4(acc[0], acc[1], acc[2], acc[3]);
        o[1] = make_float4(acc[4], acc[5], acc[6], acc[7]);
        o[2] = make_float4(acc[8], acc[9], acc[10], acc[11]);
        o[3] = make_float4(acc[12], acc[13], acc[14], acc[15]);
    }
    stats_epilogue(acc, partials, sred);
}

__global__ void k_conv2(const float* __restrict__ h1, const int* __restrict__ pcnt,
                        const uint32_t* __restrict__ pairs, const float* __restrict__ w2,
                        const float* __restrict__ scsh1, float* __restrict__ out,
                        float* __restrict__ partials, int N) {
    __shared__ float sred[4][32];
    __shared__ float sc[16], sh[16];
    if (threadIdx.x < 16) { sc[threadIdx.x] = scsh1[threadIdx.x]; sh[threadIdx.x] = scsh1[16 + threadIdx.x]; }
    __syncthreads();
    int n = blockIdx.x * blockDim.x + threadIdx.x;
    float acc[16];
    #pragma unroll
    for (int d = 0; d < 16; ++d) acc[d] = 0.f;
    if (n < N) {
        float g[16];
        #pragma unroll
        for (int c = 0; c < 16; c += 4) {
            float4 t = *(const float4*)&h1[(size_t)n * 16 + c];
            g[c]     = fmaxf(fmaf(t.x, sc[c],     sh[c]),     0.f);
            g[c + 1] = fmaxf(fmaf(t.y, sc[c + 1], sh[c + 1]), 0.f);
            g[c + 2] = fmaxf(fmaf(t.z, sc[c + 2], sh[c + 2]), 0.f);
            g[c + 3] = fmaxf(fmaf(t.w, sc[c + 3], sh[c + 3]), 0.f);
        }
        {
            const float* w = w2 + 13 * 256;
            #pragma unroll
            for (int c = 0; c < 16; ++c)
                #pragma unroll
                for (int d = 0; d < 16; ++d)
                    acc[d] = fmaf(g[c], w[c * 16 + d], acc[d]);
        }
        int m = min(pcnt[n], PCAP);
        for (int cc = 0; cc < m; ++cc) {
            uint32_t pr = pairs[(size_t)cc * N + n];
            int k = (int)(pr >> 18), idx = (int)(pr & 0x3FFFFu);
            #pragma unroll
            for (int c = 0; c < 16; c += 4) {
                float4 t = *(const float4*)&h1[(size_t)idx * 16 + c];
                g[c]     = fmaxf(fmaf(t.x, sc[c],     sh[c]),     0.f);
                g[c + 1] = fmaxf(fmaf(t.y, sc[c + 1], sh[c + 1]), 0.f);
                g[c + 2] = fmaxf(fmaf(t.z, sc[c + 2], sh[c + 2]), 0.f);
                g[c + 3] = fmaxf(fmaf(t.w, sc[c + 3], sh[c + 3]), 0.f);
            }
            const float* wk = w2 + k * 256;
            #pragma unroll
            for (int c = 0; c < 16; ++c)
                #pragma unroll
                for (int d = 0; d < 16; ++d)
                    acc[d] = fmaf(g[c], wk[c * 16 + d], acc[d]);
        }
        float4* o = (float4*)&out[(size_t)n * 16];
        o[0] = make_float4(acc[0], acc[1], acc[2], acc[3]);
        o[1] = make_float4(acc[4], acc[5], acc[6], acc[7]);
        o[2] = make_float4(acc[8], acc[9], acc[10], acc[11]);
        o[3] = make_float4(acc[12], acc[13], acc[14], acc[15]);
    }
    stats_epilogue(acc, partials, sred);
}

__global__ void k_finalize(const float* __restrict__ partials, int nb,
                           const float* __restrict__ gamma, const float* __restrict__ beta,
                           float* __restrict__ scsh, float invN) {
    __shared__ float red[32][33];
    int ch = threadIdx.x & 31;
    int rg = threadIdx.x >> 5;
    float s0 = 0.f, s1 = 0.f, s2 = 0.f, s3 = 0.f;
    int j = rg;
    for (; j + 96 < nb; j += 128) {
        s0 += partials[(size_t)(j      ) * 32 + ch];
        s1 += partials[(size_t)(j + 32 ) * 32 + ch];
        s2 += partials[(size_t)(j + 64 ) * 32 + ch];
        s3 += partials[(size_t)(j + 96 ) * 32 + ch];
    }
    for (; j < nb; j += 32) s0 += partials[(size_t)j * 32 + ch];
    red[rg][ch] = (s0 + s1) + (s2 + s3);
    __syncthreads();
    if (threadIdx.x < 32) {
        float t = 0.f;
        #pragma unroll
        for (int r = 0; r < 32; ++r) t += red[r][threadIdx.x];
        red[0][threadIdx.x] = t;
    }
    __syncthreads();
    if (threadIdx.x < 16) {
        int d = threadIdx.x;
        float mean = red[0][d] * invN;
        float var = red[0][16 + d] * invN - mean * mean;
        float s2c = gamma[d] * rsqrtf(var + BN_EPS);
        scsh[d] = s2c;
        scsh[16 + d] = beta[d] - mean * s2c;
    }
}

__global__ void k_bnrelu4(float* __restrict__ x, const float* __restrict__ scsh, int nvec) {
    __shared__ float sc[16], sh[16];
    if (threadIdx.x < 16) { sc[threadIdx.x] = scsh[threadIdx.x]; sh[threadIdx.x] = scsh[16 + threadIdx.x]; }
    __syncthreads();
    int i = blockIdx.x * blockDim.x + threadIdx.x;
    if (i < nvec) {
        float4 v = ((float4*)x)[i];
        int c0 = (i & 3) * 4;
        v.x = fmaxf(fmaf(v.x, sc[c0 + 0], sh[c0 + 0]), 0.f);
        v.y = fmaxf(fmaf(v.y, sc[c0 + 1], sh[c0 + 1]), 0.f);
        v.z = fmaxf(fmaf(v.z, sc[c0 + 2], sh[c0 + 2]), 0.f);
        v.w = fmaxf(fmaf(v.w, sc[c0 + 3], sh[c0 + 3]), 0.f);
        ((float4*)x)[i] = v;
    }
}

// ============================================================================

extern "C" void kernel_launch(void* const* d_in, const int* in_sizes, int n_in,
                              void* d_out, int out_size, void* d_ws, size_t ws_size,
                              hipStream_t stream) {
    const float* feat   = (const float*)d_in[0];
    const int*   coords = (const int*)d_in[1];
    const float* w1     = (const float*)d_in[2];
    const float* gamma1 = (const float*)d_in[3];
    const float* beta1  = (const float*)d_in[4];
    const float* w2     = (const float*)d_in[5];
    const float* gamma2 = (const float*)d_in[6];
    const float* beta2  = (const float*)d_in[7];
    float* out = (float*)d_out;
    const int N = in_sizes[0] / 3;

    const int T = 256;
    const int nb = (N + T - 1) / T;
    const int nvec = N * 16 / 4;
    const int nbv = (nvec + T - 1) / T;

    // workspace layout (64B aligned)
    char* ws = (char*)d_ws;
    size_t off = 0;
    uint32_t* bent = (uint32_t*)(ws + off);  off += (size_t)NBUCKET * 32 * 4;
    int* pcnt = (int*)(ws + off);            off += ((size_t)N * 4 + 63) & ~(size_t)63;
    uint32_t* pairs = (uint32_t*)(ws + off); off += (size_t)PCAP * N * 4;
    float* h1 = (float*)(ws + off);          off += (size_t)N * 16 * 4;
    float* p1 = (float*)(ws + off);          off += (size_t)1024 * 32 * 4;
    float* p2 = (float*)(ws + off);          off += (size_t)1024 * 32 * 4;
    float* stats = (float*)(ws + off);       // fallback only: [0:32] sc/sh1, [32:64] sc/sh2

    // one-time capability probe (host-side queries only; graph-capture safe)
    static int s_grid = 0;
    static int s_coop = -1;
    if (s_coop < 0) {
        int dev = 0;
        hipGetDevice(&dev);
        int coop = 0;
        hipDeviceGetAttribute(&coop, hipDeviceAttributeCooperativeLaunch, dev);
        hipDeviceProp_t prop{};
        hipGetDeviceProperties(&prop, dev);
        int maxB = 0;
        hipOccupancyMaxActiveBlocksPerMultiprocessor(&maxB, k_fused, T, 0);
        s_grid = maxB * prop.multiProcessorCount;
        if (s_grid > 1024) s_grid = 1024;   // partials arrays sized for 1024 blocks
        s_coop = (coop && s_grid >= 64) ? 1 : 0;
    }

    bool done = false;
    if (s_coop == 1) {
        int grid = s_grid < nb ? s_grid : nb;
        float invN = 1.f / (float)N;
        int Nv = N;
        void* args[] = { (void*)&feat, (void*)&coords, (void*)&w1, (void*)&gamma1, (void*)&beta1,
                         (void*)&w2, (void*)&gamma2, (void*)&beta2, (void*)&out,
                         (void*)&bent, (void*)&pcnt, (void*)&pairs, (void*)&h1,
                         (void*)&p1, (void*)&p2, (void*)&Nv, (void*)&invN };
        hipError_t e = hipLaunchCooperativeKernel((const void*)k_fused, dim3(grid), dim3(T),
                                                  args, 0, stream);
        done = (e == hipSuccess);
    }

    if (!done) {
        // verified 7-dispatch fallback (152.9 us)
        hipMemsetAsync(bent, 0, (size_t)NBUCKET * 32 * 4, stream);
        k_insert<<<nb, T, 0, stream>>>(coords, bent, N);
        k_build_conv1<<<nb, T, 0, stream>>>(coords, bent, feat, w1, pcnt, pairs, h1, p1, N);
        k_finalize<<<1, 1024, 0, stream>>>(p1, nb, gamma1, beta1, stats, 1.f / (float)N);
        k_conv2<<<nb, T, 0, stream>>>(h1, pcnt, pairs, w2, stats, out, p2, N);
        k_finalize<<<1, 1024, 0, stream>>>(p2, nb, gamma2, beta2, stats + 32, 1.f / (float)N);
        k_bnrelu4<<<nbv, T, 0, stream>>>(out, stats + 32, nvec);
    }
}

// Round 2
// 228.914 us; speedup vs baseline: 2.3927x; 2.3927x over previous
//
#include <hip/hip_runtime.h>
#include <stdint.h>

#define SPARSE_D 41
#define SPARSE_H 1600
#define SPARSE_W 1408
#define BN_EPS 0.001f

static constexpr int NYB = SPARSE_H / 2;          // 800
static constexpr int NBUCKET = SPARSE_D * NYB;    // 32,800
static constexpr int PCAP = 12;                   // max non-self pairs per voxel (lambda~0.056)

// bucket = z*NYB + (y>>1): 32 uint32 words (128B). word0 = count, words 1..31 = entries.
// entry: [29]=y&1, [28:18]=x (11b), [17:0]=idx ; pair: [22:18]=k, [17:0]=idx

// ---------------- scatter voxels into buckets (count in word0) ----------------
__global__ void k_insert(const int* __restrict__ coords, uint32_t* __restrict__ bent, int N) {
    int n = blockIdx.x * blockDim.x + threadIdx.x;
    if (n >= N) return;
    int4 c4 = ((const int4*)coords)[n];
    int z = c4.y, y = c4.z, x = c4.w;
    int b = z * NYB + (y >> 1);
    uint32_t e = ((uint32_t)(y & 1) << 29) | ((uint32_t)x << 18) | (uint32_t)n;
    int slot = atomicAdd((int*)&bent[(size_t)b * 32], 1) + 1;
    if (slot <= 31) bent[(size_t)b * 32 + slot] = e;
}

// ---- stats epilogue: wave shuffle reduce -> LDS -> per-block partials ----
// partials written with agent-scope RELEASE stores so the last-block finalizer
// (possibly on another XCD) sees them after the acq_rel ticket.
__device__ __forceinline__ void stats_epilogue(const float acc[16],
                                               float* __restrict__ partials,
                                               float (*sred)[32]) {
    int lid = threadIdx.x & 63;
    int wid = threadIdx.x >> 6;
    #pragma unroll
    for (int d = 0; d < 16; ++d) {
        float v = acc[d];
        float v2 = v * v;
        #pragma unroll
        for (int off = 32; off; off >>= 1) {
            v += __shfl_xor(v, off);
            v2 += __shfl_xor(v2, off);
        }
        if (lid == 0) { sred[wid][d] = v; sred[wid][16 + d] = v2; }
    }
    __syncthreads();
    if (threadIdx.x < 32) {
        float v = sred[0][threadIdx.x] + sred[1][threadIdx.x] +
                  sred[2][threadIdx.x] + sred[3][threadIdx.x];
        __hip_atomic_store(&partials[(size_t)blockIdx.x * 32 + threadIdx.x], v,
                           __ATOMIC_RELEASE, __HIP_MEMORY_SCOPE_AGENT);
    }
}

// ---- last-block finalize: reduce partials[nbk][32] -> scsh (256 threads) ----
__device__ __forceinline__ void final256(const float* __restrict__ partials, int nbk,
                                         const float* __restrict__ gamma,
                                         const float* __restrict__ beta,
                                         float* __restrict__ scsh, float invN) {
    __shared__ float red[8][33];
    int ch = threadIdx.x & 31, rg = threadIdx.x >> 5;   // 8 row-groups x 32 channels
    float s0 = 0.f, s1 = 0.f, s2 = 0.f, s3 = 0.f;
    int j = rg;
    for (; j + 24 < nbk; j += 32) {
        s0 += __hip_atomic_load(&partials[(size_t)(j     ) * 32 + ch], __ATOMIC_RELAXED, __HIP_MEMORY_SCOPE_AGENT);
        s1 += __hip_atomic_load(&partials[(size_t)(j +  8) * 32 + ch], __ATOMIC_RELAXED, __HIP_MEMORY_SCOPE_AGENT);
        s2 += __hip_atomic_load(&partials[(size_t)(j + 16) * 32 + ch], __ATOMIC_RELAXED, __HIP_MEMORY_SCOPE_AGENT);
        s3 += __hip_atomic_load(&partials[(size_t)(j + 24) * 32 + ch], __ATOMIC_RELAXED, __HIP_MEMORY_SCOPE_AGENT);
    }
    for (; j < nbk; j += 8)
        s0 += __hip_atomic_load(&partials[(size_t)j * 32 + ch], __ATOMIC_RELAXED, __HIP_MEMORY_SCOPE_AGENT);
    red[rg][ch] = (s0 + s1) + (s2 + s3);
    __syncthreads();
    if (threadIdx.x < 32) {
        float t = 0.f;
        #pragma unroll
        for (int r = 0; r < 8; ++r) t += red[r][threadIdx.x];
        red[0][threadIdx.x] = t;   // column-exclusive: thread i only touches col i
    }
    __syncthreads();
    if (threadIdx.x < 16) {
        int d = threadIdx.x;
        float mean = red[0][d] * invN;
        float var  = red[0][16 + d] * invN - mean * mean;
        float s2c  = gamma[d] * rsqrtf(var + BN_EPS);
        scsh[d] = s2c;                       // next dispatch reads these (boundary = visible)
        scsh[16 + d] = beta[d] - mean * s2c;
    }
}

// ------ fused: build pairs (regs) + conv1 (C=3->16) + BN1 stats + last-block finalize ------
__global__ void k_build_conv1(const int* __restrict__ coords, const uint32_t* __restrict__ bent,
                              const float* __restrict__ feat, const float* __restrict__ w1,
                              int* __restrict__ pcnt, uint32_t* __restrict__ pairs,
                              float* __restrict__ h1, float* __restrict__ partials,
                              uint32_t* __restrict__ ticket,
                              const float* __restrict__ gamma, const float* __restrict__ beta,
                              float* __restrict__ scsh, float invN, int N) {
    __shared__ float sred[4][32];
    __shared__ int s_last;
    int n = blockIdx.x * blockDim.x + threadIdx.x;
    float acc[16];
    #pragma unroll
    for (int d = 0; d < 16; ++d) acc[d] = 0.f;
    if (n < N) {
        int4 c4 = ((const int4*)coords)[n];
        int z = c4.y, y = c4.z, x = c4.w;

        // self term first (uniform weight pointer -> scalar loads; overlaps with probes)
        float f0 = feat[n * 3 + 0], f1 = feat[n * 3 + 1], f2 = feat[n * 3 + 2];
        const float* wd = w1 + 13 * 48;
        #pragma unroll
        for (int d = 0; d < 16; ++d)
            acc[d] = fmaf(f0, wd[d], fmaf(f1, wd[16 + d], f2 * wd[32 + d]));

        // preload all 6 bucket line0s unconditionally (masked -> bucket 0) for MLP
        int yb0 = (y - 1) >> 1;
        uint4 q0[6];
        int bix[6], mm[6];
        #pragma unroll
        for (int p = 0; p < 6; ++p) {
            int zz = z + p / 2 - 1;
            int yb = yb0 + (p & 1);
            bool v = ((unsigned)zz < SPARSE_D) & ((unsigned)yb < NYB);
            int b = v ? (zz * NYB + yb) : 0;
            bix[p] = b;
            q0[p] = *(const uint4*)&bent[(size_t)b * 32];
            mm[p] = v ? 1 : 0;
        }

        uint32_t lpairs[PCAP];
        int cnt = 0;
        #pragma unroll
        for (int p = 0; p < 6; ++p) {
            int m = mm[p] ? min((int)q0[p].x, 31) : 0;
            int yb = yb0 + (p & 1);
            int dzk = (p / 2) * 9;
            auto scan_entry = [&](uint32_t e, int slot) {
                if (slot > m) return;
                int ey = (yb << 1) + (int)(e >> 29);
                int ex = (int)((e >> 18) & 0x7FFu);
                int dy = ey - y, dx = ex - x;
                if ((unsigned)(dy + 1) > 2u || (unsigned)(dx + 1) > 2u) return;
                uint32_t idx = e & 0x3FFFFu;
                if (idx == (uint32_t)n) return;
                int k = dzk + (dy + 1) * 3 + (dx + 1);
                if (cnt < PCAP) lpairs[cnt] = ((uint32_t)k << 18) | idx;
                ++cnt;
            };
            scan_entry(q0[p].y, 1);
            scan_entry(q0[p].z, 2);
            scan_entry(q0[p].w, 3);
            for (int w = 4; w <= m; w += 4) {
                uint4 q = *(const uint4*)&bent[(size_t)bix[p] * 32 + w];
                scan_entry(q.x, w);
                scan_entry(q.y, w + 1);
                scan_entry(q.z, w + 2);
                scan_entry(q.w, w + 3);
            }
        }
        cnt = min(cnt, PCAP);
        pcnt[n] = cnt;
        for (int c = 0; c < cnt; ++c) {
            uint32_t pr = lpairs[c];
            pairs[(size_t)c * N + n] = pr;
            int k = (int)(pr >> 18), idx = (int)(pr & 0x3FFFFu);
            float g0 = feat[idx * 3 + 0], g1 = feat[idx * 3 + 1], g2 = feat[idx * 3 + 2];
            const float* wk = w1 + k * 48;     // L1-resident (5.2 KB total)
            #pragma unroll
            for (int d = 0; d < 16; ++d)
                acc[d] = fmaf(g0, wk[d], fmaf(g1, wk[16 + d], fmaf(g2, wk[32 + d], acc[d])));
        }
        float4* o = (float4*)&h1[(size_t)n * 16];
        o[0] = make_float4(acc[0], acc[1], acc[2], acc[3]);
        o[1] = make_float4(acc[4], acc[5], acc[6], acc[7]);
        o[2] = make_float4(acc[8], acc[9], acc[10], acc[11]);
        o[3] = make_float4(acc[12], acc[13], acc[14], acc[15]);
    }
    stats_epilogue(acc, partials, sred);
    __syncthreads();                 // all 32 partials stores done (vmcnt drained)
    if (threadIdx.x == 0)
        s_last = (__hip_atomic_fetch_add(ticket, 1u, __ATOMIC_ACQ_REL,
                                         __HIP_MEMORY_SCOPE_AGENT) == (uint32_t)(gridDim.x - 1));
    __syncthreads();
    if (s_last) final256(partials, (int)gridDim.x, gamma, beta, scsh, invN);
}

// ------- conv2: C=16->16, BN1+ReLU fused on load + BN2 stats + last-block finalize -------
__global__ void k_conv2(const float* __restrict__ h1, const int* __restrict__ pcnt,
                        const uint32_t* __restrict__ pairs, const float* __restrict__ w2,
                        const float* __restrict__ scsh1, float* __restrict__ out,
                        float* __restrict__ partials, uint32_t* __restrict__ ticket,
                        const float* __restrict__ gamma, const float* __restrict__ beta,
                        float* __restrict__ scsh2, float invN, int N) {
    __shared__ float sred[4][32];
    __shared__ float sc[16], sh[16];
    __shared__ int s_last;
    if (threadIdx.x < 16) { sc[threadIdx.x] = scsh1[threadIdx.x]; sh[threadIdx.x] = scsh1[16 + threadIdx.x]; }
    __syncthreads();
    int n = blockIdx.x * blockDim.x + threadIdx.x;
    float acc[16];
    #pragma unroll
    for (int d = 0; d < 16; ++d) acc[d] = 0.f;
    if (n < N) {
        float g[16];
        #pragma unroll
        for (int c = 0; c < 16; c += 4) {
            float4 t = *(const float4*)&h1[(size_t)n * 16 + c];
            g[c]     = fmaxf(fmaf(t.x, sc[c],     sh[c]),     0.f);
            g[c + 1] = fmaxf(fmaf(t.y, sc[c + 1], sh[c + 1]), 0.f);
            g[c + 2] = fmaxf(fmaf(t.z, sc[c + 2], sh[c + 2]), 0.f);
            g[c + 3] = fmaxf(fmaf(t.w, sc[c + 3], sh[c + 3]), 0.f);
        }
        {
            const float* w = w2 + 13 * 256;    // uniform -> scalar-cache loads
            #pragma unroll
            for (int c = 0; c < 16; ++c)
                #pragma unroll
                for (int d = 0; d < 16; ++d)
                    acc[d] = fmaf(g[c], w[c * 16 + d], acc[d]);
        }
        int m = min(pcnt[n], PCAP);
        for (int cc = 0; cc < m; ++cc) {
            uint32_t pr = pairs[(size_t)cc * N + n];
            int k = (int)(pr >> 18), idx = (int)(pr & 0x3FFFFu);
            #pragma unroll
            for (int c = 0; c < 16; c += 4) {
                float4 t = *(const float4*)&h1[(size_t)idx * 16 + c];
                g[c]     = fmaxf(fmaf(t.x, sc[c],     sh[c]),     0.f);
                g[c + 1] = fmaxf(fmaf(t.y, sc[c + 1], sh[c + 1]), 0.f);
                g[c + 2] = fmaxf(fmaf(t.z, sc[c + 2], sh[c + 2]), 0.f);
                g[c + 3] = fmaxf(fmaf(t.w, sc[c + 3], sh[c + 3]), 0.f);
            }
            const float* wk = w2 + k * 256;    // L1-resident (27.6 KB total)
            #pragma unroll
            for (int c = 0; c < 16; ++c)
                #pragma unroll
                for (int d = 0; d < 16; ++d)
                    acc[d] = fmaf(g[c], wk[c * 16 + d], acc[d]);
        }
        float4* o = (float4*)&out[(size_t)n * 16];
        o[0] = make_float4(acc[0], acc[1], acc[2], acc[3]);
        o[1] = make_float4(acc[4], acc[5], acc[6], acc[7]);
        o[2] = make_float4(acc[8], acc[9], acc[10], acc[11]);
        o[3] = make_float4(acc[12], acc[13], acc[14], acc[15]);
    }
    stats_epilogue(acc, partials, sred);
    __syncthreads();
    if (threadIdx.x == 0)
        s_last = (__hip_atomic_fetch_add(ticket, 1u, __ATOMIC_ACQ_REL,
                                         __HIP_MEMORY_SCOPE_AGENT) == (uint32_t)(gridDim.x - 1));
    __syncthreads();
    if (s_last) final256(partials, (int)gridDim.x, gamma, beta, scsh2, invN);
}

// ---------------- elementwise BN+ReLU (float4 per thread) ----------------
__global__ void k_bnrelu4(float* __restrict__ x, const float* __restrict__ scsh, int nvec) {
    __shared__ float sc[16], sh[16];
    if (threadIdx.x < 16) { sc[threadIdx.x] = scsh[threadIdx.x]; sh[threadIdx.x] = scsh[16 + threadIdx.x]; }
    __syncthreads();
    int i = blockIdx.x * blockDim.x + threadIdx.x;
    if (i < nvec) {
        float4 v = ((float4*)x)[i];
        int c0 = (i & 3) * 4;
        v.x = fmaxf(fmaf(v.x, sc[c0 + 0], sh[c0 + 0]), 0.f);
        v.y = fmaxf(fmaf(v.y, sc[c0 + 1], sh[c0 + 1]), 0.f);
        v.z = fmaxf(fmaf(v.z, sc[c0 + 2], sh[c0 + 2]), 0.f);
        v.w = fmaxf(fmaf(v.w, sc[c0 + 3], sh[c0 + 3]), 0.f);
        ((float4*)x)[i] = v;
    }
}

extern "C" void kernel_launch(void* const* d_in, const int* in_sizes, int n_in,
                              void* d_out, int out_size, void* d_ws, size_t ws_size,
                              hipStream_t stream) {
    const float* feat   = (const float*)d_in[0];
    const int*   coords = (const int*)d_in[1];
    const float* w1     = (const float*)d_in[2];
    const float* gamma1 = (const float*)d_in[3];
    const float* beta1  = (const float*)d_in[4];
    const float* w2     = (const float*)d_in[5];
    const float* gamma2 = (const float*)d_in[6];
    const float* beta2  = (const float*)d_in[7];
    float* out = (float*)d_out;
    const int N = in_sizes[0] / 3;

    const int T = 256;
    const int nb = (N + T - 1) / T;          // 782 blocks
    const int nvec = N * 16 / 4;
    const int nbv = (nvec + T - 1) / T;
    const float invN = 1.f / (float)N;

    // workspace layout (64B aligned)
    char* ws = (char*)d_ws;
    size_t off = 0;
    uint32_t* bent = (uint32_t*)(ws + off);  off += (size_t)NBUCKET * 32 * 4;        // 4.2 MB
    uint32_t* ctrl = (uint32_t*)(ws + off);  off += 64;                              // tickets (memset'd with bent)
    int* pcnt = (int*)(ws + off);            off += ((size_t)N * 4 + 63) & ~(size_t)63;
    uint32_t* pairs = (uint32_t*)(ws + off); off += (size_t)PCAP * N * 4;            // 9.6 MB
    float* h1 = (float*)(ws + off);          off += (size_t)N * 16 * 4;              // 12.8 MB
    float* p1 = (float*)(ws + off);          off += ((size_t)nb * 32 * 4 + 63) & ~(size_t)63;
    float* p2 = (float*)(ws + off);          off += ((size_t)nb * 32 * 4 + 63) & ~(size_t)63;
    float* stats = (float*)(ws + off);       // [0:32] sc/sh 1, [32:64] sc/sh 2

    // 5 dispatches (was 7): k_finalize kernels folded into conv kernels via
    // last-block-done ticket (agent-scope release partials + acq_rel ticket).
    hipMemsetAsync(bent, 0, (size_t)NBUCKET * 32 * 4 + 64, stream);
    k_insert<<<nb, T, 0, stream>>>(coords, bent, N);
    k_build_conv1<<<nb, T, 0, stream>>>(coords, bent, feat, w1, pcnt, pairs, h1, p1,
                                        ctrl + 0, gamma1, beta1, stats, invN, N);
    k_conv2<<<nb, T, 0, stream>>>(h1, pcnt, pairs, w2, stats, out, p2,
                                  ctrl + 1, gamma2, beta2, stats + 32, invN, N);
    k_bnrelu4<<<nbv, T, 0, stream>>>(out, stats + 32, nvec);
}

// Round 3
// 151.843 us; speedup vs baseline: 3.6072x; 1.5076x over previous
//
#include <hip/hip_runtime.h>
#include <stdint.h>

#define SPARSE_D 41
#define SPARSE_H 1600
#define SPARSE_W 1408
#define BN_EPS 0.001f

static constexpr int NYB = SPARSE_H / 2;          // 800
static constexpr int NBUCKET = SPARSE_D * NYB;    // 32,800
static constexpr int PCAP = 12;                   // max non-self pairs per voxel (lambda~0.056)

// bucket = z*NYB + (y>>1): 32 uint32 words (128B). word0 = count, words 1..31 = entries.
// entry: [29]=y&1, [28:18]=x (11b), [17:0]=idx ; pair: [22:18]=k, [17:0]=idx

// ---------------- scatter voxels into buckets + pad feat to float4 ----------------
__global__ void k_insert(const int* __restrict__ coords, const float* __restrict__ feat,
                         uint32_t* __restrict__ bent, float* __restrict__ featp, int N) {
    int n = blockIdx.x * blockDim.x + threadIdx.x;
    if (n >= N) return;
    int4 c4 = ((const int4*)coords)[n];
    int z = c4.y, y = c4.z, x = c4.w;
    int b = z * NYB + (y >> 1);
    uint32_t e = ((uint32_t)(y & 1) << 29) | ((uint32_t)x << 18) | (uint32_t)n;
    int slot = atomicAdd((int*)&bent[(size_t)b * 32], 1) + 1;
    if (slot <= 31) bent[(size_t)b * 32 + slot] = e;
    // feat 12B -> 16B stride so neighbor gathers are one dwordx4 / one cache line
    float f0 = feat[n * 3 + 0], f1 = feat[n * 3 + 1], f2 = feat[n * 3 + 2];
    ((float4*)featp)[n] = make_float4(f0, f1, f2, 0.f);
}

// ---- stats epilogue: wave shuffle reduce -> LDS -> per-block partials ----
__device__ __forceinline__ void stats_epilogue(const float acc[16],
                                               float* __restrict__ partials,
                                               float (*sred)[32]) {
    int lid = threadIdx.x & 63;
    int wid = threadIdx.x >> 6;
    #pragma unroll
    for (int d = 0; d < 16; ++d) {
        float v = acc[d];
        float v2 = v * v;
        #pragma unroll
        for (int off = 32; off; off >>= 1) {
            v += __shfl_xor(v, off);
            v2 += __shfl_xor(v2, off);
        }
        if (lid == 0) { sred[wid][d] = v; sred[wid][16 + d] = v2; }
    }
    __syncthreads();
    if (threadIdx.x < 32)
        partials[(size_t)blockIdx.x * 32 + threadIdx.x] =
            sred[0][threadIdx.x] + sred[1][threadIdx.x] +
            sred[2][threadIdx.x] + sred[3][threadIdx.x];
}

// ------ fused: build pairs (regs) + conv1 (C=3->16, weights in LDS) + BN1 stats ------
__global__ void k_build_conv1(const int* __restrict__ coords, const uint32_t* __restrict__ bent,
                              const float* __restrict__ featp, const float* __restrict__ w1,
                              int* __restrict__ pcnt, uint32_t* __restrict__ pairs,
                              float* __restrict__ h1, float* __restrict__ partials, int N) {
    __shared__ float sred[4][32];
    __shared__ float sw1[27 * 52];   // k-stride 52 floats: (52*k)%32 spreads banks, <=2-way
    for (int i = threadIdx.x; i < 27 * 48; i += 256)
        sw1[(i / 48) * 52 + (i % 48)] = w1[i];
    __syncthreads();

    int n = blockIdx.x * blockDim.x + threadIdx.x;
    float acc[16];
    #pragma unroll
    for (int d = 0; d < 16; ++d) acc[d] = 0.f;
    if (n < N) {
        int4 c4 = ((const int4*)coords)[n];
        int z = c4.y, y = c4.z, x = c4.w;

        // self term first (uniform weight pointer -> scalar loads; overlaps with probes)
        float4 f = ((const float4*)featp)[n];
        const float* wd = w1 + 13 * 48;
        #pragma unroll
        for (int d = 0; d < 16; ++d)
            acc[d] = fmaf(f.x, wd[d], fmaf(f.y, wd[16 + d], f.z * wd[32 + d]));

        // preload all 6 bucket line0s unconditionally (masked -> bucket 0) for MLP
        int yb0 = (y - 1) >> 1;
        uint4 q0[6];
        int bix[6], mm[6];
        #pragma unroll
        for (int p = 0; p < 6; ++p) {
            int zz = z + p / 2 - 1;
            int yb = yb0 + (p & 1);
            bool v = ((unsigned)zz < SPARSE_D) & ((unsigned)yb < NYB);
            int b = v ? (zz * NYB + yb) : 0;
            bix[p] = b;
            q0[p] = *(const uint4*)&bent[(size_t)b * 32];
            mm[p] = v ? 1 : 0;
        }

        uint32_t lpairs[PCAP];
        int cnt = 0;
        #pragma unroll
        for (int p = 0; p < 6; ++p) {
            int m = mm[p] ? min((int)q0[p].x, 31) : 0;
            int yb = yb0 + (p & 1);
            int dzk = (p / 2) * 9;
            auto scan_entry = [&](uint32_t e, int slot) {
                if (slot > m) return;
                int ey = (yb << 1) + (int)(e >> 29);
                int ex = (int)((e >> 18) & 0x7FFu);
                int dy = ey - y, dx = ex - x;
                if ((unsigned)(dy + 1) > 2u || (unsigned)(dx + 1) > 2u) return;
                uint32_t idx = e & 0x3FFFFu;
                if (idx == (uint32_t)n) return;
                int k = dzk + (dy + 1) * 3 + (dx + 1);
                if (cnt < PCAP) lpairs[cnt] = ((uint32_t)k << 18) | idx;
                ++cnt;
            };
            scan_entry(q0[p].y, 1);
            scan_entry(q0[p].z, 2);
            scan_entry(q0[p].w, 3);
            for (int w = 4; w <= m; w += 4) {
                uint4 q = *(const uint4*)&bent[(size_t)bix[p] * 32 + w];
                scan_entry(q.x, w);
                scan_entry(q.y, w + 1);
                scan_entry(q.z, w + 2);
                scan_entry(q.w, w + 3);
            }
        }
        cnt = min(cnt, PCAP);
        pcnt[n] = cnt;
        for (int c = 0; c < cnt; ++c) {
            uint32_t pr = lpairs[c];
            pairs[(size_t)c * N + n] = pr;
            int k = (int)(pr >> 18), idx = (int)(pr & 0x3FFFFu);
            float4 g = ((const float4*)featp)[idx];          // 1 line-request (was 3)
            const float* wk = &sw1[k * 52];                  // LDS, off the L1 path
            #pragma unroll
            for (int d = 0; d < 16; ++d)
                acc[d] = fmaf(g.x, wk[d], fmaf(g.y, wk[16 + d], fmaf(g.z, wk[32 + d], acc[d])));
        }
        float4* o = (float4*)&h1[(size_t)n * 16];
        o[0] = make_float4(acc[0], acc[1], acc[2], acc[3]);
        o[1] = make_float4(acc[4], acc[5], acc[6], acc[7]);
        o[2] = make_float4(acc[8], acc[9], acc[10], acc[11]);
        o[3] = make_float4(acc[12], acc[13], acc[14], acc[15]);
    }
    stats_epilogue(acc, partials, sred);
}

// ------- conv2: C=16->16, weights in LDS, BN1+ReLU fused on load -------
__global__ void k_conv2(const float* __restrict__ h1, const int* __restrict__ pcnt,
                        const uint32_t* __restrict__ pairs, const float* __restrict__ w2,
                        const float* __restrict__ scsh1, float* __restrict__ out,
                        float* __restrict__ partials, int N) {
    __shared__ float sred[4][32];
    __shared__ float sc[16], sh[16];
    __shared__ float sw2[27 * 260];  // 28.1 KB; k-stride 260: (260*k)%32=4k -> ~2-way max
    if (threadIdx.x < 16) { sc[threadIdx.x] = scsh1[threadIdx.x]; sh[threadIdx.x] = scsh1[16 + threadIdx.x]; }
    for (int i = threadIdx.x; i < 27 * 256; i += 256)
        sw2[(i >> 8) * 260 + (i & 255)] = w2[i];
    __syncthreads();

    int n = blockIdx.x * blockDim.x + threadIdx.x;
    float acc[16];
    #pragma unroll
    for (int d = 0; d < 16; ++d) acc[d] = 0.f;
    if (n < N) {
        float g[16];
        #pragma unroll
        for (int c = 0; c < 16; c += 4) {
            float4 t = *(const float4*)&h1[(size_t)n * 16 + c];
            g[c]     = fmaxf(fmaf(t.x, sc[c],     sh[c]),     0.f);
            g[c + 1] = fmaxf(fmaf(t.y, sc[c + 1], sh[c + 1]), 0.f);
            g[c + 2] = fmaxf(fmaf(t.z, sc[c + 2], sh[c + 2]), 0.f);
            g[c + 3] = fmaxf(fmaf(t.w, sc[c + 3], sh[c + 3]), 0.f);
        }
        {
            const float* w = w2 + 13 * 256;    // uniform -> scalar-cache loads
            #pragma unroll
            for (int c = 0; c < 16; ++c)
                #pragma unroll
                for (int d = 0; d < 16; ++d)
                    acc[d] = fmaf(g[c], w[c * 16 + d], acc[d]);
        }
        int m = min(pcnt[n], PCAP);
        for (int cc = 0; cc < m; ++cc) {
            uint32_t pr = pairs[(size_t)cc * N + n];
            int k = (int)(pr >> 18), idx = (int)(pr & 0x3FFFFu);
            #pragma unroll
            for (int c = 0; c < 16; c += 4) {
                float4 t = *(const float4*)&h1[(size_t)idx * 16 + c];
                g[c]     = fmaxf(fmaf(t.x, sc[c],     sh[c]),     0.f);
                g[c + 1] = fmaxf(fmaf(t.y, sc[c + 1], sh[c + 1]), 0.f);
                g[c + 2] = fmaxf(fmaf(t.z, sc[c + 2], sh[c + 2]), 0.f);
                g[c + 3] = fmaxf(fmaf(t.w, sc[c + 3], sh[c + 3]), 0.f);
            }
            const float* wk = &sw2[k * 260];   // LDS: no more L1 thrash (w2 = 27.6KB > L1)
            #pragma unroll
            for (int c = 0; c < 16; ++c)
                #pragma unroll
                for (int d = 0; d < 16; ++d)
                    acc[d] = fmaf(g[c], wk[c * 16 + d], acc[d]);
        }
        float4* o = (float4*)&out[(size_t)n * 16];
        o[0] = make_float4(acc[0], acc[1], acc[2], acc[3]);
        o[1] = make_float4(acc[4], acc[5], acc[6], acc[7]);
        o[2] = make_float4(acc[8], acc[9], acc[10], acc[11]);
        o[3] = make_float4(acc[12], acc[13], acc[14], acc[15]);
    }
    stats_epilogue(acc, partials, sred);
}

// ------- finalize: 1024 threads, 32 row-groups x 32 channels, 4-way ILP -------
__global__ void k_finalize(const float* __restrict__ partials, int nb,
                           const float* __restrict__ gamma, const float* __restrict__ beta,
                           float* __restrict__ scsh, float invN) {
    __shared__ float red[32][33];
    int ch = threadIdx.x & 31;
    int rg = threadIdx.x >> 5;   // 0..31
    float s0 = 0.f, s1 = 0.f, s2 = 0.f, s3 = 0.f;
    int j = rg;
    for (; j + 96 < nb; j += 128) {
        s0 += partials[(size_t)(j      ) * 32 + ch];
        s1 += partials[(size_t)(j + 32 ) * 32 + ch];
        s2 += partials[(size_t)(j + 64 ) * 32 + ch];
        s3 += partials[(size_t)(j + 96 ) * 32 + ch];
    }
    for (; j < nb; j += 32) s0 += partials[(size_t)j * 32 + ch];
    red[rg][ch] = (s0 + s1) + (s2 + s3);
    __syncthreads();
    if (threadIdx.x < 32) {
        float t = 0.f;
        #pragma unroll
        for (int r = 0; r < 32; ++r) t += red[r][threadIdx.x];
        red[0][threadIdx.x] = t;
    }
    __syncthreads();
    if (threadIdx.x < 16) {
        int d = threadIdx.x;
        float mean = red[0][d] * invN;
        float var = red[0][16 + d] * invN - mean * mean;
        float s2c = gamma[d] * rsqrtf(var + BN_EPS);
        scsh[d] = s2c;
        scsh[16 + d] = beta[d] - mean * s2c;
    }
}

// ---------------- elementwise BN+ReLU (float4 per thread) ----------------
__global__ void k_bnrelu4(float* __restrict__ x, const float* __restrict__ scsh, int nvec) {
    __shared__ float sc[16], sh[16];
    if (threadIdx.x < 16) { sc[threadIdx.x] = scsh[threadIdx.x]; sh[threadIdx.x] = scsh[16 + threadIdx.x]; }
    __syncthreads();
    int i = blockIdx.x * blockDim.x + threadIdx.x;
    if (i < nvec) {
        float4 v = ((float4*)x)[i];
        int c0 = (i & 3) * 4;
        v.x = fmaxf(fmaf(v.x, sc[c0 + 0], sh[c0 + 0]), 0.f);
        v.y = fmaxf(fmaf(v.y, sc[c0 + 1], sh[c0 + 1]), 0.f);
        v.z = fmaxf(fmaf(v.z, sc[c0 + 2], sh[c0 + 2]), 0.f);
        v.w = fmaxf(fmaf(v.w, sc[c0 + 3], sh[c0 + 3]), 0.f);
        ((float4*)x)[i] = v;
    }
}

extern "C" void kernel_launch(void* const* d_in, const int* in_sizes, int n_in,
                              void* d_out, int out_size, void* d_ws, size_t ws_size,
                              hipStream_t stream) {
    const float* feat   = (const float*)d_in[0];
    const int*   coords = (const int*)d_in[1];
    const float* w1     = (const float*)d_in[2];
    const float* gamma1 = (const float*)d_in[3];
    const float* beta1  = (const float*)d_in[4];
    const float* w2     = (const float*)d_in[5];
    const float* gamma2 = (const float*)d_in[6];
    const float* beta2  = (const float*)d_in[7];
    float* out = (float*)d_out;
    const int N = in_sizes[0] / 3;

    const int T = 256;
    const int nb = (N + T - 1) / T;          // 782 blocks
    const int nvec = N * 16 / 4;
    const int nbv = (nvec + T - 1) / T;

    // workspace layout (64B aligned)
    char* ws = (char*)d_ws;
    size_t off = 0;
    uint32_t* bent = (uint32_t*)(ws + off);  off += (size_t)NBUCKET * 32 * 4;        // 4.2 MB
    int* pcnt = (int*)(ws + off);            off += ((size_t)N * 4 + 63) & ~(size_t)63;
    uint32_t* pairs = (uint32_t*)(ws + off); off += (size_t)PCAP * N * 4;            // 9.6 MB
    float* h1 = (float*)(ws + off);          off += (size_t)N * 16 * 4;              // 12.8 MB
    float* featp = (float*)(ws + off);       off += (size_t)N * 4 * 4;               // 3.2 MB
    float* partials = (float*)(ws + off);    off += ((size_t)nb * 32 * 4 + 63) & ~(size_t)63;
    float* stats = (float*)(ws + off);       // [0:32] sc/sh 1, [32:64] sc/sh 2

    hipMemsetAsync(bent, 0, (size_t)NBUCKET * 32 * 4, stream);
    k_insert<<<nb, T, 0, stream>>>(coords, feat, bent, featp, N);
    k_build_conv1<<<nb, T, 0, stream>>>(coords, bent, featp, w1, pcnt, pairs, h1, partials, N);
    k_finalize<<<1, 1024, 0, stream>>>(partials, nb, gamma1, beta1, stats, 1.f / (float)N);
    k_conv2<<<nb, T, 0, stream>>>(h1, pcnt, pairs, w2, stats, out, partials, N);
    k_finalize<<<1, 1024, 0, stream>>>(partials, nb, gamma2, beta2, stats + 32, 1.f / (float)N);
    k_bnrelu4<<<nbv, T, 0, stream>>>(out, stats + 32, nvec);
}